// Round 2
// baseline (455.447 us; speedup 1.0000x reference)
//
#include <hip/hip_runtime.h>
#include <hip/hip_bf16.h>
#include <float.h>

// DensityLoss: B=4, N=8192, D=3, K=10 nearest neighbors (excluding self).
// avg_dist[b,i] = mean of 10 smallest distances (self at d=0 excluded
// implicitly: we keep the 11 smallest d^2 including self; sqrt(0)=0
// contributes nothing to the sum, divide by 10).
// out = mean_b( var_{ddof=1}_i( avg_dist[b,i] ) )

#define N_PTS 8192
#define NB 4
#define KNN 11              // k+1 including self
#define TILE 2048           // candidate points staged in LDS per iteration
#define ROWS_PER_BLOCK 64   // one row per lane; all 4 waves share the rows
#define THREADS 256
#define WAVES 4
#define CAND_PER_WAVE (TILE / WAVES)   // 512 candidates per wave per tile
#define MERGE_STRIDE 45     // 44 entries + 1 pad (bank-conflict light)

__global__ __launch_bounds__(THREADS) void knn_avg_kernel(
    const float* __restrict__ pc, float* __restrict__ avg_out) {
  __shared__ __align__(16) float sPts[TILE * 4];        // xyz_ padded float4
  __shared__ float sMerge[ROWS_PER_BLOCK * MERGE_STRIDE];

  const int rowBlocks = N_PTS / ROWS_PER_BLOCK;         // 128
  const int b = blockIdx.x / rowBlocks;
  const int rowBase = (blockIdx.x % rowBlocks) * ROWS_PER_BLOCK;
  const int tid = threadIdx.x;
  const int wid = tid >> 6;
  const int lane = tid & 63;
  const int row = rowBase + lane;

  const float* __restrict__ batch = pc + (size_t)b * N_PTS * 3;

  // query point (each lane's own row; same across the 4 waves)
  const float xi = batch[row * 3 + 0];
  const float yi = batch[row * 3 + 1];
  const float zi = batch[row * 3 + 2];

  float w[KNN];
#pragma unroll
  for (int s = 0; s < KNN; ++s) w[s] = FLT_MAX;
  float worst = FLT_MAX;

  for (int t = 0; t < N_PTS / TILE; ++t) {
    __syncthreads();
    // cooperative tile load: TILE*3 floats, coalesced, repacked to float4
    const float* __restrict__ src = batch + t * TILE * 3;
#pragma unroll
    for (int k = 0; k < (TILE * 3) / THREADS; ++k) {    // 24 iters
      const int f = k * THREADS + tid;
      const float v = src[f];
      const int p = f / 3;
      const int c = f - p * 3;
      sPts[p * 4 + c] = v;
    }
    __syncthreads();

    const int j0 = wid * CAND_PER_WAVE;
    for (int j = j0; j < j0 + CAND_PER_WAVE; ++j) {
      const float4 pj = *reinterpret_cast<const float4*>(&sPts[j * 4]);
      const float dx = xi - pj.x;
      const float dy = yi - pj.y;
      const float dz = zi - pj.z;
      const float d2 = fmaf(dx, dx, fmaf(dy, dy, dz * dz));
      if (d2 < worst) {   // rarely taken at wave level after warm-up
        bool done = false;
#pragma unroll
        for (int s = 0; s < KNN; ++s) {
          const bool hit = (!done) && (w[s] == worst);
          if (hit) w[s] = d2;
          done = done || hit;
        }
        float m = w[0];
#pragma unroll
        for (int s = 1; s < KNN; ++s) m = fmaxf(m, w[s]);
        worst = m;
      }
    }
  }

  // dump each wave's top-11 for merge
#pragma unroll
  for (int s = 0; s < KNN; ++s)
    sMerge[lane * MERGE_STRIDE + wid * KNN + s] = w[s];
  __syncthreads();

  if (tid < ROWS_PER_BLOCK) {
    const int r = tid;
    float best[KNN];
#pragma unroll
    for (int s = 0; s < KNN; ++s) best[s] = FLT_MAX;
    float worst2 = FLT_MAX;
    for (int c = 0; c < WAVES * KNN; ++c) {
      const float d2 = sMerge[r * MERGE_STRIDE + c];
      if (d2 < worst2) {
        bool done = false;
#pragma unroll
        for (int s = 0; s < KNN; ++s) {
          const bool hit = (!done) && (best[s] == worst2);
          if (hit) best[s] = d2;
          done = done || hit;
        }
        float m = best[0];
#pragma unroll
        for (int s = 1; s < KNN; ++s) m = fmaxf(m, best[s]);
        worst2 = m;
      }
    }
    float sum = 0.0f;
#pragma unroll
    for (int s = 0; s < KNN; ++s) sum += sqrtf(best[s]);
    avg_out[b * N_PTS + rowBase + r] = sum * (1.0f / 10.0f);
  }
}

__global__ void var_reduce_kernel(const float* __restrict__ avg,
                                  float* __restrict__ out) {
  __shared__ double sS[WAVES], sS2[WAVES];
  const int tid = threadIdx.x;   // 256 threads
  const int wid = tid >> 6;
  const int lane = tid & 63;
  double total = 0.0;
  for (int b = 0; b < NB; ++b) {
    double s = 0.0, s2 = 0.0;
    for (int i = tid; i < N_PTS; i += THREADS) {
      const double x = (double)avg[b * N_PTS + i];
      s += x;
      s2 += x * x;
    }
#pragma unroll
    for (int off = 32; off > 0; off >>= 1) {
      s += __shfl_down(s, off, 64);
      s2 += __shfl_down(s2, off, 64);
    }
    if (lane == 0) { sS[wid] = s; sS2[wid] = s2; }
    __syncthreads();
    if (tid == 0) {
      const double S = sS[0] + sS[1] + sS[2] + sS[3];
      const double S2 = sS2[0] + sS2[1] + sS2[2] + sS2[3];
      const double var =
          (S2 - S * S / (double)N_PTS) / (double)(N_PTS - 1);
      total += var;
    }
    __syncthreads();
  }
  if (tid == 0) out[0] = (float)(total / NB);
}

extern "C" void kernel_launch(void* const* d_in, const int* in_sizes, int n_in,
                              void* d_out, int out_size, void* d_ws,
                              size_t ws_size, hipStream_t stream) {
  const float* pc = (const float*)d_in[0];
  float* out = (float*)d_out;
  float* ws = (float*)d_ws;   // B*N floats = 128 KiB

  const dim3 grid(NB * (N_PTS / ROWS_PER_BLOCK));   // 512 blocks
  knn_avg_kernel<<<grid, THREADS, 0, stream>>>(pc, ws);
  var_reduce_kernel<<<1, THREADS, 0, stream>>>(ws, out);
}

// Round 3
// 325.714 us; speedup vs baseline: 1.3983x; 1.3983x over previous
//
#include <hip/hip_runtime.h>
#include <hip/hip_bf16.h>
#include <float.h>

// DensityLoss: B=4, N=8192, D=3, K=10 NN (excluding self).
// Keep 11 smallest d^2 per row (incl. self at 0; sqrt(0) adds nothing),
// avg = sum(sqrt)/10. out = mean_b var_ddof1_i(avg[b,i]).
//
// Layout: 512 blocks x 256 thr. Block owns 64 rows (lane = row), 4 waves
// split the 8192 candidates 4-way via LDS tiles. Top-11 kept SORTED
// DESCENDING per lane; insert is the depth-2 formula
//   w[s] = max(w[s+1], min(w[s], d2))   (w[11] = -inf)
// Waves share per-row thresholds through LDS every 128 candidates so each
// wave's acceptance test reflects ~4x the candidates actually seen.

#define N_PTS 8192
#define NB 4
#define KNN 11
#define TILE 2048
#define THREADS 256
#define WAVES 4
#define CAND_PER_WAVE (TILE / WAVES)   // 512
#define CHUNK 128                      // candidates between threshold syncs
#define CHUNKS_PER_TILE (CAND_PER_WAVE / CHUNK) // 4
#define MERGE_STRIDE 45

__global__ __launch_bounds__(THREADS) void knn_avg_kernel(
    const float* __restrict__ pc, double* __restrict__ wsd) {
  __shared__ __align__(16) float sPts[TILE * 4];            // xyz_ float4
  __shared__ float sMerge[64 * MERGE_STRIDE];
  __shared__ float sThr[2][WAVES][64];                      // double-buffered

  const int rowBlocks = N_PTS / 64;                         // 128
  const int b = blockIdx.x / rowBlocks;
  const int rowBase = (blockIdx.x % rowBlocks) * 64;
  const int tid = threadIdx.x;
  const int wid = tid >> 6;
  const int lane = tid & 63;
  const int row = rowBase + lane;

  const float* __restrict__ batch = pc + (size_t)b * N_PTS * 3;

  const float xi = batch[row * 3 + 0];
  const float yi = batch[row * 3 + 1];
  const float zi = batch[row * 3 + 2];

  float w[KNN + 1];            // sorted descending, w[KNN] = -inf sentinel
#pragma unroll
  for (int s = 0; s < KNN; ++s) w[s] = FLT_MAX;
  w[KNN] = -FLT_MAX;
  float thrS = FLT_MAX;        // min over waves of w[0] (stale ok)
  int par = 0;

  for (int t = 0; t < N_PTS / TILE; ++t) {
    // stage tile (previous chunk's barrier guarantees sPts is free)
    const float* __restrict__ src = batch + t * TILE * 3;
#pragma unroll
    for (int k = 0; k < (TILE * 3) / THREADS; ++k) {        // 24
      const int f = k * THREADS + tid;
      const float v = src[f];
      const int p = f / 3;
      const int c = f - p * 3;
      sPts[p * 4 + c] = v;
    }
    __syncthreads();

    const int j0 = wid * CAND_PER_WAVE;
    for (int c = 0; c < CHUNKS_PER_TILE; ++c) {
      const int jb = j0 + c * CHUNK;
#pragma unroll 4
      for (int j = jb; j < jb + CHUNK; ++j) {
        const float4 pj = *reinterpret_cast<const float4*>(&sPts[j * 4]);
        const float dx = xi - pj.x;
        const float dy = yi - pj.y;
        const float dz = zi - pj.z;
        const float d2 = fmaf(dx, dx, fmaf(dy, dy, dz * dz));
        const float thr = fminf(thrS, w[0]);
        if (d2 < thr) {
#pragma unroll
          for (int s = 0; s < KNN; ++s)
            w[s] = fmaxf(w[s + 1], fminf(w[s], d2));
        }
      }
      // publish / gather shared threshold (double-buffered, 1 barrier)
      sThr[par][wid][lane] = w[0];
      __syncthreads();
      float m = sThr[par][0][lane];
#pragma unroll
      for (int q = 1; q < WAVES; ++q) m = fminf(m, sThr[par][q][lane]);
      thrS = m;
      par ^= 1;
    }
  }

  // merge the 4 waves' top-11 per row
#pragma unroll
  for (int s = 0; s < KNN; ++s)
    sMerge[lane * MERGE_STRIDE + wid * KNN + s] = w[s];
  __syncthreads();

  if (tid < 64) {
    float best[KNN + 1];
#pragma unroll
    for (int s = 0; s < KNN; ++s) best[s] = FLT_MAX;
    best[KNN] = -FLT_MAX;
    for (int c = 0; c < WAVES * KNN; ++c) {
      const float d2 = sMerge[tid * MERGE_STRIDE + c];
#pragma unroll
      for (int s = 0; s < KNN; ++s)
        best[s] = fmaxf(best[s + 1], fminf(best[s], d2));
    }
    float sum = 0.0f;
#pragma unroll
    for (int s = 0; s < KNN; ++s) sum += sqrtf(best[s]);
    const double avg = (double)(sum * (1.0f / 10.0f));

    // wave-level (tid 0..63 = wave 0) f64 reduction of S, S2
    double S = avg, S2 = avg * avg;
#pragma unroll
    for (int off = 32; off > 0; off >>= 1) {
      S += __shfl_down(S, off, 64);
      S2 += __shfl_down(S2, off, 64);
    }
    if (tid == 0) {
      atomicAdd(&wsd[2 * b + 0], S);
      atomicAdd(&wsd[2 * b + 1], S2);
    }
  }
}

__global__ void finalize_kernel(const double* __restrict__ wsd,
                                float* __restrict__ out) {
  if (threadIdx.x == 0) {
    double total = 0.0;
#pragma unroll
    for (int b = 0; b < NB; ++b) {
      const double S = wsd[2 * b + 0];
      const double S2 = wsd[2 * b + 1];
      total += (S2 - S * S / (double)N_PTS) / (double)(N_PTS - 1);
    }
    out[0] = (float)(total / NB);
  }
}

extern "C" void kernel_launch(void* const* d_in, const int* in_sizes, int n_in,
                              void* d_out, int out_size, void* d_ws,
                              size_t ws_size, hipStream_t stream) {
  const float* pc = (const float*)d_in[0];
  float* out = (float*)d_out;
  double* wsd = (double*)d_ws;   // 8 doubles: (S, S2) per batch

  hipMemsetAsync(d_ws, 0, 2 * NB * sizeof(double), stream);
  const dim3 grid(NB * (N_PTS / 64));   // 512 blocks
  knn_avg_kernel<<<grid, THREADS, 0, stream>>>(pc, wsd);
  finalize_kernel<<<1, 64, 0, stream>>>(wsd, out);
}

// Round 5
// 229.890 us; speedup vs baseline: 1.9811x; 1.4168x over previous
//
#include <hip/hip_runtime.h>
#include <hip/hip_bf16.h>
#include <float.h>

// DensityLoss: B=4, N=8192, D=3, K=10 NN (excluding self).
// Keep 11 smallest d^2 per row (incl. self at 0; sqrt(0) adds nothing),
// avg = sum(sqrt)/10. out = mean_b var_ddof1_i(avg[b,i]).
//
// Strategy: fully BRANCHLESS selection. w[0..10] kept sorted descending
// (w[11]=w[12]=-inf). Two candidates (lo<=hi) merge in with
//   w[s] = max3( w[s+2], min(w[s+1], hi), min(w[s], lo) )
// (standard 2-way merge network; 3 VALU/slot, v_max3-fusable), applied
// UNCONDITIONALLY per pair — no divergent guard, no if-conversion bloat,
// no threshold machinery. 512 thr/block (8 waves) for 4 waves/SIMD.

#define N_PTS 8192
#define NB 4
#define KNN 11
#define TILE 2048
#define THREADS 512
#define WAVES 8
#define CAND_PER_WAVE (TILE / WAVES)        // 256 per tile
#define MERGE_STRIDE (WAVES * KNN + 1)      // 89 (odd => 2-way LDS alias, free)

__device__ __forceinline__ float dist2(const float4 p, float xi, float yi,
                                       float zi) {
  const float dx = xi - p.x;
  const float dy = yi - p.y;
  const float dz = zi - p.z;
  return fmaf(dx, dx, fmaf(dy, dy, dz * dz));
}

__device__ __forceinline__ void insert_pair(float* w, float da, float db) {
  const float lo = fminf(da, db);
  const float hi = fmaxf(da, db);
  // ascending in-place is safe: slot s reads only indices >= s (old values)
#pragma unroll
  for (int s = 0; s < KNN; ++s)
    w[s] = fmaxf(fmaxf(w[s + 2], fminf(w[s + 1], hi)), fminf(w[s], lo));
}

__global__ __launch_bounds__(THREADS) void knn_avg_kernel(
    const float* __restrict__ pc, double* __restrict__ wsd) {
  __shared__ __align__(16) float4 sPts[TILE];
  __shared__ float sMerge[64 * MERGE_STRIDE];

  const int b = blockIdx.x >> 7;              // /128 row-blocks per batch
  const int rowBase = (blockIdx.x & 127) << 6;
  const int tid = threadIdx.x;
  const int wid = tid >> 6;
  const int lane = tid & 63;
  const int row = rowBase + lane;

  const float* __restrict__ batch = pc + (size_t)b * N_PTS * 3;

  const float xi = batch[row * 3 + 0];
  const float yi = batch[row * 3 + 1];
  const float zi = batch[row * 3 + 2];

  float w[KNN + 2];                           // sorted desc + 2 sentinels
#pragma unroll
  for (int s = 0; s < KNN; ++s) w[s] = FLT_MAX;
  w[KNN] = -FLT_MAX;
  w[KNN + 1] = -FLT_MAX;

  for (int t = 0; t < N_PTS / TILE; ++t) {
    __syncthreads();                          // sPts free to overwrite
    const float* __restrict__ src = batch + t * TILE * 3;
#pragma unroll
    for (int k = 0; k < (TILE * 3) / THREADS; ++k) {    // 12
      const int f = k * THREADS + tid;
      const float v = src[f];
      const int p = f / 3;
      const int c = f - p * 3;
      reinterpret_cast<float*>(&sPts[p])[c] = v;
    }
    __syncthreads();

    const int j0 = wid * CAND_PER_WAVE;
#pragma unroll 4
    for (int j = j0; j < j0 + CAND_PER_WAVE; j += 2) {
      const float4 pa = sPts[j];
      const float4 pb = sPts[j + 1];
      insert_pair(w, dist2(pa, xi, yi, zi), dist2(pb, xi, yi, zi));
    }
  }

  // dump each wave's sorted top-11 per row, then merge 88 -> 11
#pragma unroll
  for (int s = 0; s < KNN; ++s)
    sMerge[lane * MERGE_STRIDE + wid * KNN + s] = w[s];
  __syncthreads();

  if (tid < 64) {
    float best[KNN + 2];
#pragma unroll
    for (int s = 0; s < KNN; ++s) best[s] = FLT_MAX;
    best[KNN] = -FLT_MAX;
    best[KNN + 1] = -FLT_MAX;
    const float* m = &sMerge[tid * MERGE_STRIDE];
    for (int c = 0; c < WAVES * KNN; c += 2)
      insert_pair(best, m[c], m[c + 1]);

    float sum = 0.0f;
#pragma unroll
    for (int s = 0; s < KNN; ++s) sum += sqrtf(best[s]);
    const double avg = (double)(sum * (1.0f / 10.0f));

    double S = avg, S2 = avg * avg;
#pragma unroll
    for (int off = 32; off > 0; off >>= 1) {
      S += __shfl_down(S, off, 64);
      S2 += __shfl_down(S2, off, 64);
    }
    if (tid == 0) {
      atomicAdd(&wsd[2 * b + 0], S);
      atomicAdd(&wsd[2 * b + 1], S2);
    }
  }
}

__global__ void finalize_kernel(const double* __restrict__ wsd,
                                float* __restrict__ out) {
  if (threadIdx.x == 0) {
    double total = 0.0;
#pragma unroll
    for (int b = 0; b < NB; ++b) {
      const double S = wsd[2 * b + 0];
      const double S2 = wsd[2 * b + 1];
      total += (S2 - S * S / (double)N_PTS) / (double)(N_PTS - 1);
    }
    out[0] = (float)(total / NB);
  }
}

extern "C" void kernel_launch(void* const* d_in, const int* in_sizes, int n_in,
                              void* d_out, int out_size, void* d_ws,
                              size_t ws_size, hipStream_t stream) {
  const float* pc = (const float*)d_in[0];
  float* out = (float*)d_out;
  double* wsd = (double*)d_ws;   // 8 doubles: (S, S2) per batch

  hipMemsetAsync(d_ws, 0, 2 * NB * sizeof(double), stream);
  const dim3 grid(NB * (N_PTS / 64));   // 512 blocks
  knn_avg_kernel<<<grid, THREADS, 0, stream>>>(pc, wsd);
  finalize_kernel<<<1, 64, 0, stream>>>(wsd, out);
}

// Round 9
// 226.816 us; speedup vs baseline: 2.0080x; 1.0136x over previous
//
#include <hip/hip_runtime.h>
#include <hip/hip_bf16.h>
#include <float.h>

// DensityLoss: B=4, N=8192, D=3, K=10 NN (excluding self).
// Keep 11 smallest d^2 per row (incl. self at 0; sqrt(0) adds nothing),
// avg = sum(sqrt)/10. out = mean_b var_ddof1_i(avg[b,i]).
//
// R6 structure: NO LDS candidate staging. Candidate addresses are
// wave-uniform (readfirstlane-forced) -> scalar/broadcast loads from L2
// (each batch is 96 KB, L2-resident). 1024-thr blocks (16 waves), block
// owns 64 rows (lane = row), candidates split 16-way; 2 blocks/CU =
// 8 waves/SIMD. Branchless sorted-descending top-11, 2-candidate merge:
//   w[s] = max3( w[s+2], min(w[s+1], hi), min(w[s], lo) )
// Final variance fused via last-block-done counter (device-scope atomics).

#define N_PTS 8192
#define NB 4
#define KNN 11
#define THREADS 1024
#define WAVES 16
#define CAND_PER_WAVE (N_PTS / WAVES)    // 512
#define MERGE_STRIDE (WAVES * KNN + 1)   // 177 (odd -> conflict-free)
#define NBLOCKS (NB * (N_PTS / 64))      // 512

__device__ __forceinline__ float dist2f(float px, float py, float pz,
                                        float xi, float yi, float zi) {
  const float dx = xi - px;
  const float dy = yi - py;
  const float dz = zi - pz;
  return fmaf(dx, dx, fmaf(dy, dy, dz * dz));
}

__device__ __forceinline__ void insert_pair(float* w, float da, float db) {
  const float lo = fminf(da, db);
  const float hi = fmaxf(da, db);
  // ascending in-place safe: slot s reads only indices >= s (old values)
#pragma unroll
  for (int s = 0; s < KNN; ++s)
    w[s] = fmaxf(fmaxf(w[s + 2], fminf(w[s + 1], hi)), fminf(w[s], lo));
}

__global__ __launch_bounds__(THREADS, 8) void knn_fused_kernel(
    const float* __restrict__ pc, double* __restrict__ wsd,
    unsigned int* __restrict__ done_cnt, float* __restrict__ out) {
  __shared__ float sMerge[64 * MERGE_STRIDE];   // 45.3 KB

  const int b = blockIdx.x >> 7;                // 128 row-groups per batch
  const int rowBase = (blockIdx.x & 127) << 6;
  const int tid = threadIdx.x;
  const int wid = __builtin_amdgcn_readfirstlane(tid >> 6);  // wave-uniform
  const int lane = tid & 63;
  const int row = rowBase + lane;

  const float* __restrict__ batch = pc + (size_t)b * (N_PTS * 3);

  const float xi = batch[row * 3 + 0];
  const float yi = batch[row * 3 + 1];
  const float zi = batch[row * 3 + 2];

  float w[KNN + 2];                             // sorted desc + 2 sentinels
#pragma unroll
  for (int s = 0; s < KNN; ++s) w[s] = FLT_MAX;
  w[KNN] = -FLT_MAX;
  w[KNN + 1] = -FLT_MAX;

  // wave-uniform candidate pointer -> scalar/broadcast loads
  const float* __restrict__ cp = batch + wid * (CAND_PER_WAVE * 3);
#pragma unroll 4
  for (int j = 0; j < CAND_PER_WAVE; j += 2) {
    const float ax = cp[0], ay = cp[1], az = cp[2];
    const float bx = cp[3], by = cp[4], bz = cp[5];
    cp += 6;
    insert_pair(w, dist2f(ax, ay, az, xi, yi, zi),
                dist2f(bx, by, bz, xi, yi, zi));
  }

  // publish each wave's sorted top-11 per row; merge 176 -> 11
#pragma unroll
  for (int s = 0; s < KNN; ++s)
    sMerge[lane * MERGE_STRIDE + wid * KNN + s] = w[s];
  __syncthreads();

  if (tid < 64) {
    float best[KNN + 2];
#pragma unroll
    for (int s = 0; s < KNN; ++s) best[s] = FLT_MAX;
    best[KNN] = -FLT_MAX;
    best[KNN + 1] = -FLT_MAX;
    const float* m = &sMerge[tid * MERGE_STRIDE];
#pragma unroll 2
    for (int c = 0; c < WAVES * KNN; c += 2)
      insert_pair(best, m[c], m[c + 1]);

    float sum = 0.0f;
#pragma unroll
    for (int s = 0; s < KNN; ++s) sum += sqrtf(best[s]);
    const double avg = (double)(sum * (1.0f / 10.0f));

    double S = avg, S2 = avg * avg;
#pragma unroll
    for (int off = 32; off > 0; off >>= 1) {
      S += __shfl_down(S, off, 64);
      S2 += __shfl_down(S2, off, 64);
    }
    if (tid == 0) {
      atomicAdd(&wsd[2 * b + 0], S);
      atomicAdd(&wsd[2 * b + 1], S2);
    }
  }

  // last-block-done finalize (device-scope atomics; cross-XCD safe reads)
  if (tid == 0) {
    __threadfence();
    const unsigned int old = atomicAdd(done_cnt, 1u);
    if (old == NBLOCKS - 1) {
      double total = 0.0;
#pragma unroll
      for (int bb = 0; bb < NB; ++bb) {
        const double S = atomicAdd(&wsd[2 * bb + 0], 0.0);
        const double S2 = atomicAdd(&wsd[2 * bb + 1], 0.0);
        total += (S2 - S * S / (double)N_PTS) / (double)(N_PTS - 1);
      }
      out[0] = (float)(total / NB);
    }
  }
}

extern "C" void kernel_launch(void* const* d_in, const int* in_sizes, int n_in,
                              void* d_out, int out_size, void* d_ws,
                              size_t ws_size, hipStream_t stream) {
  const float* pc = (const float*)d_in[0];
  float* out = (float*)d_out;
  double* wsd = (double*)d_ws;                       // 8 doubles (S,S2)/batch
  unsigned int* done_cnt = (unsigned int*)((char*)d_ws + 2 * NB * sizeof(double));

  hipMemsetAsync(d_ws, 0, 2 * NB * sizeof(double) + sizeof(unsigned int),
                 stream);
  knn_fused_kernel<<<NBLOCKS, THREADS, 0, stream>>>(pc, wsd, done_cnt, out);
}

// Round 11
// 210.091 us; speedup vs baseline: 2.1679x; 1.0796x over previous
//
#include <hip/hip_runtime.h>
#include <hip/hip_bf16.h>
#include <float.h>

// DensityLoss: B=4, N=8192, D=3, K=10 NN (excluding self).
// Keep 11 smallest d^2 per row (incl. self at 0; sqrt(0) adds nothing),
// avg = sum(sqrt)/10. out = mean_b var_ddof1_i(avg[b,i]).
//
// R10: selection network runs on INTEGER bit patterns. d^2 >= 0, and for
// non-negative IEEE floats, float order == signed-int order of the bits.
// int min/max (v_min_i32/v_max_i32/v_max3_i32) carry no NaN-canonicalization
// baggage, so the 11-slot merge network is truly 3 VALU/slot:
//   w[s] = max3( w[s+2], min(w[s+1], hi), min(w[s], lo) )
// Sentinels: 0x7F800000 (+inf) above, -1 below (all d^2 ints are >= 0).
// Structure otherwise identical to R9: wave-uniform scalar candidate loads
// from L2, 1024-thr blocks (16 waves, 8 waves/SIMD), fused finalize.

#define N_PTS 8192
#define NB 4
#define KNN 11
#define THREADS 1024
#define WAVES 16
#define CAND_PER_WAVE (N_PTS / WAVES)    // 512
#define MERGE_STRIDE (WAVES * KNN + 1)   // 177 (odd -> conflict-free)
#define NBLOCKS (NB * (N_PTS / 64))      // 512
#define IPOSINF 0x7F800000               // +inf bit pattern

__device__ __forceinline__ float dist2f(float px, float py, float pz,
                                        float xi, float yi, float zi) {
  const float dx = xi - px;
  const float dy = yi - py;
  const float dz = zi - pz;
  return fmaf(dx, dx, fmaf(dy, dy, dz * dz));
}

__device__ __forceinline__ int imin2(int a, int b) { return a < b ? a : b; }
__device__ __forceinline__ int imax2(int a, int b) { return a > b ? a : b; }

__device__ __forceinline__ void insert_pair_i(int* w, float da, float db) {
  const int ia = __float_as_int(da);
  const int ib = __float_as_int(db);
  const int lo = imin2(ia, ib);
  const int hi = imax2(ia, ib);
  // ascending in-place safe: slot s reads only indices >= s (old values);
  // imax2(imax2(..),..) fuses to v_max3_i32
#pragma unroll
  for (int s = 0; s < KNN; ++s)
    w[s] = imax2(imax2(w[s + 2], imin2(w[s + 1], hi)), imin2(w[s], lo));
}

__global__ __launch_bounds__(THREADS, 8) void knn_fused_kernel(
    const float* __restrict__ pc, double* __restrict__ wsd,
    unsigned int* __restrict__ done_cnt, float* __restrict__ out) {
  __shared__ int sMerge[64 * MERGE_STRIDE];   // 45.3 KB

  const int b = blockIdx.x >> 7;                // 128 row-groups per batch
  const int rowBase = (blockIdx.x & 127) << 6;
  const int tid = threadIdx.x;
  const int wid = __builtin_amdgcn_readfirstlane(tid >> 6);  // wave-uniform
  const int lane = tid & 63;
  const int row = rowBase + lane;

  const float* __restrict__ batch = pc + (size_t)b * (N_PTS * 3);

  const float xi = batch[row * 3 + 0];
  const float yi = batch[row * 3 + 1];
  const float zi = batch[row * 3 + 2];

  int w[KNN + 2];                               // sorted desc (as ints)
#pragma unroll
  for (int s = 0; s < KNN; ++s) w[s] = IPOSINF;
  w[KNN] = -1;
  w[KNN + 1] = -1;

  // wave-uniform candidate pointer -> scalar/broadcast loads
  const float* __restrict__ cp = batch + wid * (CAND_PER_WAVE * 3);
#pragma unroll 4
  for (int j = 0; j < CAND_PER_WAVE; j += 2) {
    const float ax = cp[0], ay = cp[1], az = cp[2];
    const float bx = cp[3], by = cp[4], bz = cp[5];
    cp += 6;
    insert_pair_i(w, dist2f(ax, ay, az, xi, yi, zi),
                  dist2f(bx, by, bz, xi, yi, zi));
  }

  // publish each wave's sorted top-11 per row; merge 176 -> 11
#pragma unroll
  for (int s = 0; s < KNN; ++s)
    sMerge[lane * MERGE_STRIDE + wid * KNN + s] = w[s];
  __syncthreads();

  if (tid < 64) {
    int best[KNN + 2];
#pragma unroll
    for (int s = 0; s < KNN; ++s) best[s] = IPOSINF;
    best[KNN] = -1;
    best[KNN + 1] = -1;
    const int* m = &sMerge[tid * MERGE_STRIDE];
#pragma unroll 2
    for (int c = 0; c < WAVES * KNN; c += 2) {
      const int ia = m[c];
      const int ib = m[c + 1];
      const int lo = imin2(ia, ib);
      const int hi = imax2(ia, ib);
#pragma unroll
      for (int s = 0; s < KNN; ++s)
        best[s] =
            imax2(imax2(best[s + 2], imin2(best[s + 1], hi)),
                  imin2(best[s], lo));
    }

    float sum = 0.0f;
#pragma unroll
    for (int s = 0; s < KNN; ++s) sum += sqrtf(__int_as_float(best[s]));
    const double avg = (double)(sum * (1.0f / 10.0f));

    double S = avg, S2 = avg * avg;
#pragma unroll
    for (int off = 32; off > 0; off >>= 1) {
      S += __shfl_down(S, off, 64);
      S2 += __shfl_down(S2, off, 64);
    }
    if (tid == 0) {
      atomicAdd(&wsd[2 * b + 0], S);
      atomicAdd(&wsd[2 * b + 1], S2);
    }
  }

  // last-block-done finalize (device-scope atomics; cross-XCD safe reads)
  if (tid == 0) {
    __threadfence();
    const unsigned int old = atomicAdd(done_cnt, 1u);
    if (old == NBLOCKS - 1) {
      double total = 0.0;
#pragma unroll
      for (int bb = 0; bb < NB; ++bb) {
        const double S = atomicAdd(&wsd[2 * bb + 0], 0.0);
        const double S2 = atomicAdd(&wsd[2 * bb + 1], 0.0);
        total += (S2 - S * S / (double)N_PTS) / (double)(N_PTS - 1);
      }
      out[0] = (float)(total / NB);
    }
  }
}

extern "C" void kernel_launch(void* const* d_in, const int* in_sizes, int n_in,
                              void* d_out, int out_size, void* d_ws,
                              size_t ws_size, hipStream_t stream) {
  const float* pc = (const float*)d_in[0];
  float* out = (float*)d_out;
  double* wsd = (double*)d_ws;                       // 8 doubles (S,S2)/batch
  unsigned int* done_cnt = (unsigned int*)((char*)d_ws + 2 * NB * sizeof(double));

  hipMemsetAsync(d_ws, 0, 2 * NB * sizeof(double) + sizeof(unsigned int),
                 stream);
  knn_fused_kernel<<<NBLOCKS, THREADS, 0, stream>>>(pc, wsd, done_cnt, out);
}